// Round 1
// baseline (1424.571 us; speedup 1.0000x reference)
//
#include <hip/hip_runtime.h>

// ---------------------------------------------------------------------------
// DecomposingAttnProcessor on MI355X (gfx950), all-bf16 MFMA pipeline.
// Stages: cvt(fp32->bf16) -> GEMM q/k/vT -> fused component-softmax attention
//         -> GEMM out (fp32).
// ---------------------------------------------------------------------------

typedef unsigned short u16;
typedef unsigned int   u32;

#define NHS   50331648ULL   /* 8*4096*1536 */
#define NEHS  1892352ULL    /* 8*154*1536  */
#define NW    2359296ULL    /* 1536*1536   */
#define NVT   1966080ULL    /* 8*1536*160  */

using bf16x8 = __attribute__((ext_vector_type(8))) short;
using f32x4  = __attribute__((ext_vector_type(4))) float;

__device__ __forceinline__ u16 f2bf(float f) {
  union { float f; u32 u; } x{f};
  u32 r = (x.u + 0x7fffu + ((x.u >> 16) & 1u)) >> 16;   // RNE, inputs finite
  return (u16)r;
}

__device__ __forceinline__ void gload_lds16(const u16* g, u16* s) {
  // async global->LDS, 16B per lane; LDS dest = wave-uniform base + lane*16
  __builtin_amdgcn_global_load_lds((const __attribute__((address_space(1))) void*)g,
                                   (__attribute__((address_space(3))) void*)s,
                                   16, 0, 0);
}

// ---------------------------------------------------------------------------
// fp32 -> bf16 elementwise conversion (vectorized float4 -> ushort4)
// ---------------------------------------------------------------------------
__global__ void cvt_bf16(const float* __restrict__ src, u16* __restrict__ dst, int n4) {
  int idx = blockIdx.x * blockDim.x + threadIdx.x;
  int stride = gridDim.x * blockDim.x;
  for (int i = idx; i < n4; i += stride) {
    float4 v = ((const float4*)src)[i];
    ushort4 o;
    o.x = f2bf(v.x); o.y = f2bf(v.y); o.z = f2bf(v.z); o.w = f2bf(v.w);
    ((ushort4*)dst)[i] = o;
  }
}

// ---------------------------------------------------------------------------
// C[M,1536] = A[M,K]*Bw[1536,K]^T + bias   (A,Bw bf16; torch-Linear layout)
// 128x128 block tile, BK=32, 256 thr = 4 waves (2x2 of 64x64), 16x16x32 MFMA.
// MODE 0: fp32 out   MODE 1: bf16 out   MODE 2: bf16 out transposed for V:
//         C_vt[bc][col][t] with row = bc*154 + t, t-dim padded to 160.
// ---------------------------------------------------------------------------
template <int MODE>
__global__ __launch_bounds__(256)
void gemm_bt(const u16* __restrict__ A, const u16* __restrict__ Bw,
             const float* __restrict__ bias, void* __restrict__ Cv,
             int M, int K) {
  const int N = 1536;
  __shared__ __align__(16) u16 As[4096];   // 128 rows x 32 (bf16)
  __shared__ __align__(16) u16 Bs[4096];
  const int tid  = threadIdx.x;
  const int wv   = tid >> 6;
  const int lane = tid & 63;
  const int wr = wv >> 1, wc = wv & 1;
  const int l16 = lane & 15, quad = lane >> 4;
  const int m0 = blockIdx.y * 128, n0 = blockIdx.x * 128;
  const int r = tid >> 2, c8 = (tid & 3) * 8;

  int ra0 = m0 + r;      if (ra0 > M - 1) ra0 = M - 1;   // M-edge clamp (loads)
  int ra1 = m0 + 64 + r; if (ra1 > M - 1) ra1 = M - 1;
  const u16* a0 = A  + (size_t)ra0 * K + c8;
  const u16* a1 = A  + (size_t)ra1 * K + c8;
  const u16* b0 = Bw + (size_t)(n0 + r) * K + c8;
  const u16* b1 = Bw + (size_t)(n0 + 64 + r) * K + c8;
  u16* asd0 = &As[tid * 8];
  u16* asd1 = &As[2048 + tid * 8];
  u16* bsd0 = &Bs[tid * 8];
  u16* bsd1 = &Bs[2048 + tid * 8];

  f32x4 acc[4][4];
#pragma unroll
  for (int i = 0; i < 4; ++i)
#pragma unroll
    for (int j = 0; j < 4; ++j) acc[i][j] = {0.f, 0.f, 0.f, 0.f};

  for (int kt = 0; kt < K; kt += 32) {
    __syncthreads();
    gload_lds16(a0 + kt, asd0);
    gload_lds16(a1 + kt, asd1);
    gload_lds16(b0 + kt, bsd0);
    gload_lds16(b1 + kt, bsd1);
    __syncthreads();
    bf16x8 af[4], bfr[4];
#pragma unroll
    for (int i = 0; i < 4; ++i) {
      af[i]  = *(const bf16x8*)&As[(wr * 64 + i * 16 + l16) * 32 + quad * 8];
      bfr[i] = *(const bf16x8*)&Bs[(wc * 64 + i * 16 + l16) * 32 + quad * 8];
    }
#pragma unroll
    for (int i = 0; i < 4; ++i)
#pragma unroll
      for (int j = 0; j < 4; ++j)
        acc[i][j] = __builtin_amdgcn_mfma_f32_16x16x32_bf16(af[i], bfr[j], acc[i][j], 0, 0, 0);
  }

#pragma unroll
  for (int i = 0; i < 4; ++i) {
    const int rb = m0 + wr * 64 + i * 16 + quad * 4;
#pragma unroll
    for (int j = 0; j < 4; ++j) {
      const int col = n0 + wc * 64 + j * 16 + l16;
      const float bvs = bias[col];
#pragma unroll
      for (int rr = 0; rr < 4; ++rr) {
        const int row = rb + rr;
        if (row < M) {
          float v = acc[i][j][rr] + bvs;
          if (MODE == 0) {
            ((float*)Cv)[(size_t)row * N + col] = v;
          } else if (MODE == 1) {
            ((u16*)Cv)[(size_t)row * N + col] = f2bf(v);
          } else {
            const int bc = row / 154;
            const int t  = row - bc * 154;
            ((u16*)Cv)[((size_t)bc * 1536 + col) * 160 + t] = f2bf(v);
          }
        }
      }
    }
  }
}

// ---------------------------------------------------------------------------
// Fused attention: component softmax + key renormalization + PV, all MFMA.
// grid (64 s-tiles, 24 heads, 2 batches), 256 thr. Wave w owns s-rows
// [s0+16w, s0+16w+16) for ALL 4 components -> softmax over c is in-register.
// LDS (exactly 160 KiB):
//   [0, 40960)  u16 : K as [c][ks2][160][32]  then  V^T as [c][ks5][64][32]
//   [40960, 81920) : w (normalized, bf16) as [c][64][160]
// ---------------------------------------------------------------------------
__global__ __launch_bounds__(256, 1)
void attn_kernel(const u16* __restrict__ qg, const u16* __restrict__ kg,
                 const u16* __restrict__ vtg, u16* __restrict__ og) {
  __shared__ __align__(16) u16 lds[81920];
  u16* wb = lds + 40960;

  const int tid  = threadIdx.x;
  const int wv   = tid >> 6;
  const int lane = tid & 63;
  const int l16 = lane & 15, quad = lane >> 4;
  const int s0 = blockIdx.x * 64;
  const int h  = blockIdx.y;
  const int b  = blockIdx.z;

  // ---- stage K -> lds[c][ks][t][.] ; dest dword index == idx by layout ----
  for (int idx = tid; idx < 20480; idx += 256) {
    const int c = idx / 5120, r0 = idx % 5120;
    const int ks = r0 / 2560, r2 = r0 % 2560;
    const int t = r2 >> 4, i = r2 & 15;
    u32 val = 0;
    if (t < 154) {
      const u32* src = (const u32*)(kg + ((size_t)((c * 2 + b) * 154 + t)) * 1536 + h * 64 + ks * 32);
      val = src[i];
    }
    ((u32*)lds)[idx] = val;
  }
  __syncthreads();

  // ---- per-wave q A-fragments straight from global (16B contiguous) ----
  bf16x8 qa[4][2];
#pragma unroll
  for (int c = 0; c < 4; ++c) {
    const u16* qrow = qg + ((size_t)((c * 2 + b) * 4096 + s0 + wv * 16 + l16)) * 1536 + h * 64;
#pragma unroll
    for (int ks = 0; ks < 2; ++ks)
      qa[c][ks] = *(const bf16x8*)(qrow + ks * 32 + quad * 8);
  }

  // ---- scores: D[s][t] = q . k  (10 t-tiles x 2 k-steps x 4 comps) ----
  f32x4 sc[4][10];
#pragma unroll
  for (int c = 0; c < 4; ++c)
#pragma unroll
    for (int nt = 0; nt < 10; ++nt) sc[c][nt] = {0.f, 0.f, 0.f, 0.f};

#pragma unroll
  for (int nt = 0; nt < 10; ++nt)
#pragma unroll
    for (int c = 0; c < 4; ++c)
#pragma unroll
      for (int ks = 0; ks < 2; ++ks) {
        bf16x8 kf = *(const bf16x8*)&lds[((c * 2 + ks) * 160 + nt * 16 + l16) * 32 + quad * 8];
        sc[c][nt] = __builtin_amdgcn_mfma_f32_16x16x32_bf16(qa[c][ks], kf, sc[c][nt], 0, 0, 0);
      }

  // ---- softmax over components (in-register) + t-row sums ----
  float rs[4][4];
#pragma unroll
  for (int c = 0; c < 4; ++c)
#pragma unroll
    for (int rr = 0; rr < 4; ++rr) rs[c][rr] = 0.f;

#pragma unroll
  for (int nt = 0; nt < 10; ++nt) {
    const int t = nt * 16 + l16;
    const bool ok = (t < 154);
#pragma unroll
    for (int rr = 0; rr < 4; ++rr) {
      float v0 = sc[0][nt][rr] * 0.125f;
      float v1 = sc[1][nt][rr] * 0.125f;
      float v2 = sc[2][nt][rr] * 0.125f;
      float v3 = sc[3][nt][rr] * 0.125f;
      float m = fmaxf(fmaxf(v0, v1), fmaxf(v2, v3));
      float e0 = __expf(v0 - m), e1 = __expf(v1 - m);
      float e2 = __expf(v2 - m), e3 = __expf(v3 - m);
      float inv = 1.f / (e0 + e1 + e2 + e3);
      float w0 = ok ? e0 * inv : 0.f;   // positional mask: kills pad garbage/NaN
      float w1 = ok ? e1 * inv : 0.f;
      float w2 = ok ? e2 * inv : 0.f;
      float w3 = ok ? e3 * inv : 0.f;
      sc[0][nt][rr] = w0; sc[1][nt][rr] = w1; sc[2][nt][rr] = w2; sc[3][nt][rr] = w3;
      rs[0][rr] += w0; rs[1][rr] += w1; rs[2][rr] += w2; rs[3][rr] += w3;
    }
  }
  // reduce over t (= over the 16-lane l16 group; quad preserved)
#pragma unroll
  for (int c = 0; c < 4; ++c)
#pragma unroll
    for (int rr = 0; rr < 4; ++rr) {
      float v = rs[c][rr];
      v += __shfl_xor(v, 1); v += __shfl_xor(v, 2);
      v += __shfl_xor(v, 4); v += __shfl_xor(v, 8);
      rs[c][rr] = 1.f / (v + 1e-8f);
    }
  // write normalized w (C-layout -> LDS row-major = A-layout for PV)
#pragma unroll
  for (int c = 0; c < 4; ++c)
#pragma unroll
    for (int nt = 0; nt < 10; ++nt) {
      const int t = nt * 16 + l16;
#pragma unroll
      for (int rr = 0; rr < 4; ++rr) {
        const int srow = wv * 16 + quad * 4 + rr;
        wb[(c * 64 + srow) * 160 + t] = f2bf(sc[c][nt][rr] * rs[c][rr]);
      }
    }
  __syncthreads();

  // ---- stage V^T -> lds[c][ks5][dh64][.] ; dest dword index == idx ----
  for (int idx = tid; idx < 20480; idx += 256) {
    const int c = idx / 5120, r0 = idx % 5120;
    const int ks = r0 / 1024, r2 = r0 % 1024;
    const int dh = r2 >> 4, tp = r2 & 15;
    const u32* src = (const u32*)(vtg + ((size_t)((c * 2 + b) * 1536 + h * 64 + dh)) * 160);
    ((u32*)lds)[idx] = src[ks * 16 + tp];
  }
  __syncthreads();

  // ---- PV: out[s][dh] = sum_t w[s][t] * V[t][dh] ----
  f32x4 oacc[4][4];
#pragma unroll
  for (int c = 0; c < 4; ++c)
#pragma unroll
    for (int nd = 0; nd < 4; ++nd) oacc[c][nd] = {0.f, 0.f, 0.f, 0.f};

#pragma unroll
  for (int c = 0; c < 4; ++c)
#pragma unroll
    for (int ks = 0; ks < 5; ++ks) {
      bf16x8 wa = *(const bf16x8*)&wb[(c * 64 + wv * 16 + l16) * 160 + ks * 32 + quad * 8];
#pragma unroll
      for (int nd = 0; nd < 4; ++nd) {
        bf16x8 vf = *(const bf16x8*)&lds[((c * 5 + ks) * 64 + nd * 16 + l16) * 32 + quad * 8];
        oacc[c][nd] = __builtin_amdgcn_mfma_f32_16x16x32_bf16(wa, vf, oacc[c][nd], 0, 0, 0);
      }
    }

  // ---- store attention output (bf16, head-major D layout) ----
#pragma unroll
  for (int c = 0; c < 4; ++c)
#pragma unroll
    for (int nd = 0; nd < 4; ++nd)
#pragma unroll
      for (int rr = 0; rr < 4; ++rr) {
        const int srow = s0 + wv * 16 + quad * 4 + rr;
        og[((size_t)((c * 2 + b) * 4096 + srow)) * 1536 + h * 64 + nd * 16 + l16] =
            f2bf(oacc[c][nd][rr]);
      }
}

// ---------------------------------------------------------------------------
extern "C" void kernel_launch(void* const* d_in, const int* in_sizes, int n_in,
                              void* d_out, int out_size, void* d_ws, size_t ws_size,
                              hipStream_t stream) {
  (void)in_sizes; (void)n_in; (void)out_size; (void)ws_size;
  const float* hs  = (const float*)d_in[0];
  const float* ehs = (const float*)d_in[1];
  const float* Wq  = (const float*)d_in[2];
  const float* bq  = (const float*)d_in[3];
  const float* Wk  = (const float*)d_in[4];
  const float* bk  = (const float*)d_in[5];
  const float* Wv  = (const float*)d_in[6];
  const float* bv  = (const float*)d_in[7];
  const float* Wo  = (const float*)d_in[8];
  const float* bo  = (const float*)d_in[9];
  float* out = (float*)d_out;

  u16* ws   = (u16*)d_ws;
  u16* hsb  = ws;               // [8*4096, 1536] bf16
  u16* ehsb = hsb + NHS;        // [8*154, 1536]  bf16
  u16* wqb  = ehsb + NEHS;
  u16* wkb  = wqb + NW;
  u16* wvb  = wkb + NW;
  u16* wob  = wvb + NW;
  u16* qb   = wob + NW;         // q  [8*4096, 1536] bf16
  u16* kgb  = qb + NHS;         // k  [8*154, 1536]  bf16
  u16* vtb  = kgb + NEHS;       // v^T [8][1536][160] bf16
  u16* atb  = vtb + NVT;        // attn out [8*4096, 1536] bf16

  auto cvt = [&](const float* s, u16* d, size_t n) {
    int n4 = (int)(n / 4);
    int blocks = (n4 + 255) / 256;
    if (blocks > 8192) blocks = 8192;
    cvt_bf16<<<blocks, 256, 0, stream>>>(s, d, n4);
  };
  cvt(hs, hsb, NHS);
  cvt(ehs, ehsb, NEHS);
  cvt(Wq, wqb, NW);
  cvt(Wk, wkb, NW);
  cvt(Wv, wvb, NW);
  cvt(Wo, wob, NW);

  gemm_bt<1><<<dim3(12, 256), 256, 0, stream>>>(hsb, wqb, bq, qb, 32768, 1536);
  gemm_bt<1><<<dim3(12, 10),  256, 0, stream>>>(ehsb, wkb, bk, kgb, 1232, 1536);
  gemm_bt<2><<<dim3(12, 10),  256, 0, stream>>>(ehsb, wvb, bv, vtb, 1232, 1536);

  attn_kernel<<<dim3(64, 24, 2), 256, 0, stream>>>(qb, kgb, vtb, atb);

  gemm_bt<0><<<dim3(12, 256), 256, 0, stream>>>(atb, wob, bo, out, 32768, 1536);
}

// Round 2
// 1071.967 us; speedup vs baseline: 1.3289x; 1.3289x over previous
//
#include <hip/hip_runtime.h>

// ---------------------------------------------------------------------------
// DecomposingAttnProcessor on MI355X (gfx950), all-bf16 MFMA pipeline.
// Stages: cvt(fp32->bf16) -> GEMM q/k/vT -> fused component-softmax attention
//         -> GEMM out (fp32).
// ---------------------------------------------------------------------------

typedef unsigned short u16;
typedef unsigned int   u32;

#define NHS   50331648ULL   /* 8*4096*1536 */
#define NEHS  1892352ULL    /* 8*154*1536  */
#define NW    2359296ULL    /* 1536*1536   */
#define NVT   1966080ULL    /* 8*1536*160  */

using bf16x8 = __attribute__((ext_vector_type(8))) short;
using f32x4  = __attribute__((ext_vector_type(4))) float;

__device__ __forceinline__ u16 f2bf(float f) {
  union { float f; u32 u; } x{f};
  u32 r = (x.u + 0x7fffu + ((x.u >> 16) & 1u)) >> 16;   // RNE, inputs finite
  return (u16)r;
}

__device__ __forceinline__ void gload_lds16(const u16* g, u16* s) {
  // async global->LDS, 16B per lane; LDS dest = wave-uniform base + lane*16
  __builtin_amdgcn_global_load_lds((const __attribute__((address_space(1))) void*)g,
                                   (__attribute__((address_space(3))) void*)s,
                                   16, 0, 0);
}

// ---------------------------------------------------------------------------
// fp32 -> bf16 elementwise conversion (vectorized float4 -> ushort4)
// ---------------------------------------------------------------------------
__global__ void cvt_bf16(const float* __restrict__ src, u16* __restrict__ dst, int n4) {
  int idx = blockIdx.x * blockDim.x + threadIdx.x;
  int stride = gridDim.x * blockDim.x;
  for (int i = idx; i < n4; i += stride) {
    float4 v = ((const float4*)src)[i];
    ushort4 o;
    o.x = f2bf(v.x); o.y = f2bf(v.y); o.z = f2bf(v.z); o.w = f2bf(v.w);
    ((ushort4*)dst)[i] = o;
  }
}

// ---------------------------------------------------------------------------
// C[M,1536] = A[M,K]*Bw[1536,K]^T + bias   (A,Bw bf16; torch-Linear layout)
// 128x128 block tile, BK=32, 256 thr = 4 waves (2x2 of 64x64), 16x16x32 MFMA.
// MODE 0: fp32 out   MODE 1: bf16 out   MODE 2: bf16 out transposed for V:
//         C_vt[bc][col][t] with row = bc*154 + t, t-dim padded to 160.
// ---------------------------------------------------------------------------
template <int MODE>
__global__ __launch_bounds__(256)
void gemm_bt(const u16* __restrict__ A, const u16* __restrict__ Bw,
             const float* __restrict__ bias, void* __restrict__ Cv,
             int M, int K) {
  const int N = 1536;
  __shared__ __align__(16) u16 As[4096];   // 128 rows x 32 (bf16)
  __shared__ __align__(16) u16 Bs[4096];
  const int tid  = threadIdx.x;
  const int wv   = tid >> 6;
  const int lane = tid & 63;
  const int wr = wv >> 1, wc = wv & 1;
  const int l16 = lane & 15, quad = lane >> 4;
  const int m0 = blockIdx.y * 128, n0 = blockIdx.x * 128;
  const int r = tid >> 2, c8 = (tid & 3) * 8;

  int ra0 = m0 + r;      if (ra0 > M - 1) ra0 = M - 1;   // M-edge clamp (loads)
  int ra1 = m0 + 64 + r; if (ra1 > M - 1) ra1 = M - 1;
  const u16* a0 = A  + (size_t)ra0 * K + c8;
  const u16* a1 = A  + (size_t)ra1 * K + c8;
  const u16* b0 = Bw + (size_t)(n0 + r) * K + c8;
  const u16* b1 = Bw + (size_t)(n0 + 64 + r) * K + c8;
  u16* asd0 = &As[tid * 8];
  u16* asd1 = &As[2048 + tid * 8];
  u16* bsd0 = &Bs[tid * 8];
  u16* bsd1 = &Bs[2048 + tid * 8];

  f32x4 acc[4][4];
#pragma unroll
  for (int i = 0; i < 4; ++i)
#pragma unroll
    for (int j = 0; j < 4; ++j) acc[i][j] = {0.f, 0.f, 0.f, 0.f};

  for (int kt = 0; kt < K; kt += 32) {
    __syncthreads();
    gload_lds16(a0 + kt, asd0);
    gload_lds16(a1 + kt, asd1);
    gload_lds16(b0 + kt, bsd0);
    gload_lds16(b1 + kt, bsd1);
    __syncthreads();
    bf16x8 af[4], bfr[4];
#pragma unroll
    for (int i = 0; i < 4; ++i) {
      af[i]  = *(const bf16x8*)&As[(wr * 64 + i * 16 + l16) * 32 + quad * 8];
      bfr[i] = *(const bf16x8*)&Bs[(wc * 64 + i * 16 + l16) * 32 + quad * 8];
    }
#pragma unroll
    for (int i = 0; i < 4; ++i)
#pragma unroll
      for (int j = 0; j < 4; ++j)
        acc[i][j] = __builtin_amdgcn_mfma_f32_16x16x32_bf16(af[i], bfr[j], acc[i][j], 0, 0, 0);
  }

#pragma unroll
  for (int i = 0; i < 4; ++i) {
    const int rb = m0 + wr * 64 + i * 16 + quad * 4;
#pragma unroll
    for (int j = 0; j < 4; ++j) {
      const int col = n0 + wc * 64 + j * 16 + l16;
      const float bvs = bias[col];
#pragma unroll
      for (int rr = 0; rr < 4; ++rr) {
        const int row = rb + rr;
        if (row < M) {
          float v = acc[i][j][rr] + bvs;
          if (MODE == 0) {
            ((float*)Cv)[(size_t)row * N + col] = v;
          } else if (MODE == 1) {
            ((u16*)Cv)[(size_t)row * N + col] = f2bf(v);
          } else {
            const int bc = row / 154;
            const int t  = row - bc * 154;
            ((u16*)Cv)[((size_t)bc * 1536 + col) * 160 + t] = f2bf(v);
          }
        }
      }
    }
  }
}

// ---------------------------------------------------------------------------
// Fused attention v2: component softmax + key renorm + PV, all MFMA.
// grid (64 s-tiles, 24 heads, 2 batches), 256 thr. Wave w owns s-rows
// [s0+16w, +16) for ALL 4 components -> softmax over c is in-register.
//
// LDS = 80 KiB (2 blocks/CU):
//   phase 1: K as [c][ks2][160 t][32] (chunk-XOR-swizzled), async-staged.
//   phase 2 (K dead): double-buffered per-component slots overlaid on K:
//     slotW[p] = [64 s][160 t] bf16 (20KB), slotV[p] = [ks5][64 dh][32] (20KB)
//     c-pipeline: stage V_{c+1} (async) + write w_{c+1} while PV_c runs.
//   w writes are wave-local (each wave reads only its own 16 s-rows).
// XOR swizzle chunk' = chunk ^ ((row>>1)&3): every 16-lane phase of a
// ds_read_b128 covers all 32 banks exactly 2x (free, m136).
// ---------------------------------------------------------------------------
__global__ __launch_bounds__(256, 2)
void attn_kernel(const u16* __restrict__ qg, const u16* __restrict__ kg,
                 const u16* __restrict__ vtg, u16* __restrict__ og) {
  __shared__ __align__(16) u16 lds[40960];   // 80 KiB

  const int tid  = threadIdx.x;
  const int wv   = tid >> 6;
  const int lane = tid & 63;
  const int l16 = lane & 15, quad = lane >> 4;
  const int s0 = blockIdx.x * 64;
  const int h  = blockIdx.y;
  const int b  = blockIdx.z;
  const int swz = ((quad ^ ((l16 >> 1) & 3)) * 8);  // lane-const read swizzle (u16)

  // ---- stage K (async, 20 x 16B per thread), source-side chunk swizzle ----
  // LDS: [c][ks][t][32 u16], 16B-chunk L = p*256+tid, row r=L>>2, chunk=L&3
  {
    const u16* kbase = kg + (size_t)b * 154 * 1536 + h * 64;
#pragma unroll
    for (int p = 0; p < 20; ++p) {
      const int L = p * 256 + tid;
      const int r = L >> 2;            // (c*2+ks)*160 + t
      const int t = r % 160;
      const int cks = r / 160;         // c*2+ks
      const int c = cks >> 1, ks = cks & 1;
      const int csrc = ((L & 3) ^ ((t >> 1) & 3)) * 8;
      const u16* src = kbase + ((size_t)c * 308 + t) * 1536 + ks * 32 + csrc;
      gload_lds16(src, &lds[(size_t)L * 8]);
    }
  }

  // ---- per-wave q A-fragments straight from global (16B contiguous) ----
  bf16x8 qa[4][2];
#pragma unroll
  for (int c = 0; c < 4; ++c) {
    const u16* qrow = qg + ((size_t)((c * 2 + b) * 4096 + s0 + wv * 16 + l16)) * 1536 + h * 64;
#pragma unroll
    for (int ks = 0; ks < 2; ++ks)
      qa[c][ks] = *(const bf16x8*)(qrow + ks * 32 + quad * 8);
  }
  __syncthreads();   // K staged (barrier drains vmcnt)

  // ---- scores: D[s][t] = q . k ----
  f32x4 sc[4][10];
#pragma unroll
  for (int c = 0; c < 4; ++c)
#pragma unroll
    for (int nt = 0; nt < 10; ++nt) sc[c][nt] = {0.f, 0.f, 0.f, 0.f};

#pragma unroll
  for (int nt = 0; nt < 10; ++nt)
#pragma unroll
    for (int c = 0; c < 4; ++c)
#pragma unroll
      for (int ks = 0; ks < 2; ++ks) {
        bf16x8 kf = *(const bf16x8*)&lds[((c * 2 + ks) * 160 + nt * 16 + l16) * 32 + swz];
        sc[c][nt] = __builtin_amdgcn_mfma_f32_16x16x32_bf16(qa[c][ks], kf, sc[c][nt], 0, 0, 0);
      }

  // ---- softmax over components (in-register) + t-row sums ----
  float rs[4][4];
#pragma unroll
  for (int c = 0; c < 4; ++c)
#pragma unroll
    for (int rr = 0; rr < 4; ++rr) rs[c][rr] = 0.f;

#pragma unroll
  for (int nt = 0; nt < 10; ++nt) {
    const int t = nt * 16 + l16;
    const bool ok = (t < 154);
#pragma unroll
    for (int rr = 0; rr < 4; ++rr) {
      float v0 = sc[0][nt][rr] * 0.125f;
      float v1 = sc[1][nt][rr] * 0.125f;
      float v2 = sc[2][nt][rr] * 0.125f;
      float v3 = sc[3][nt][rr] * 0.125f;
      float m = fmaxf(fmaxf(v0, v1), fmaxf(v2, v3));
      float e0 = __expf(v0 - m), e1 = __expf(v1 - m);
      float e2 = __expf(v2 - m), e3 = __expf(v3 - m);
      float inv = 1.f / (e0 + e1 + e2 + e3);
      float w0 = ok ? e0 * inv : 0.f;   // positional mask kills pad garbage/NaN
      float w1 = ok ? e1 * inv : 0.f;
      float w2 = ok ? e2 * inv : 0.f;
      float w3 = ok ? e3 * inv : 0.f;
      sc[0][nt][rr] = w0; sc[1][nt][rr] = w1; sc[2][nt][rr] = w2; sc[3][nt][rr] = w3;
      rs[0][rr] += w0; rs[1][rr] += w1; rs[2][rr] += w2; rs[3][rr] += w3;
    }
  }
#pragma unroll
  for (int c = 0; c < 4; ++c)
#pragma unroll
    for (int rr = 0; rr < 4; ++rr) {
      float v = rs[c][rr];
      v += __shfl_xor(v, 1); v += __shfl_xor(v, 2);
      v += __shfl_xor(v, 4); v += __shfl_xor(v, 8);
      rs[c][rr] = 1.f / (v + 1e-8f);
    }

  __syncthreads();   // all waves done reading K -> region reusable

  // ---- per-component pipelined PV over overlaid double-buffered slots ----
  // slotW[p] @ u16 offset p*10240 : [64 s][160 t]
  // slotV[p] @ u16 offset 20480 + p*10240 : [ks5][64 dh][32]
  const u16* vbase = vtg + ((size_t)b * 1536 + h * 64) * 160;

  auto stage_v = [&](int c, int par) {
    const u16* vb = vbase + (size_t)c * 2 * 1536 * 160;
    u16* slot = &lds[20480 + par * 10240];
#pragma unroll
    for (int p = 0; p < 5; ++p) {
      const int L = p * 256 + tid;
      const int row = L >> 2;          // ks*64 + dh
      const int ks = row >> 6, dh = row & 63;
      const int csrc = ((L & 3) ^ ((dh >> 1) & 3)) * 8;
      gload_lds16(vb + dh * 160 + ks * 32 + csrc, &slot[(size_t)L * 8]);
    }
  };

  auto write_w = [&](int c, int par) {
    u16* slot = &lds[par * 10240];
#pragma unroll
    for (int nt = 0; nt < 10; ++nt) {
#pragma unroll
      for (int rr = 0; rr < 4; ++rr) {
        const int srow = wv * 16 + quad * 4 + rr;
        const int t = nt * 16 + l16;
        const int cl = ((t >> 3) & 3) ^ ((srow >> 1) & 3);
        slot[srow * 160 + (t >> 5) * 32 + cl * 8 + (t & 7)] =
            f2bf(sc[c][nt][rr] * rs[c][rr]);
      }
    }
  };

  f32x4 oacc[4][4];
#pragma unroll
  for (int c = 0; c < 4; ++c)
#pragma unroll
    for (int nd = 0; nd < 4; ++nd) oacc[c][nd] = {0.f, 0.f, 0.f, 0.f};

  stage_v(0, 0);
  write_w(0, 0);
#pragma unroll
  for (int c = 0; c < 4; ++c) {
    __syncthreads();                 // V_c arrived; slot[(c+1)&1] free
    if (c < 3) { stage_v(c + 1, (c + 1) & 1); write_w(c + 1, (c + 1) & 1); }
    const int par = c & 1;
    const u16* sw = &lds[par * 10240];
    const u16* sv = &lds[20480 + par * 10240];
#pragma unroll
    for (int ks = 0; ks < 5; ++ks) {
      bf16x8 wa = *(const bf16x8*)&sw[(wv * 16 + l16) * 160 + ks * 32 + swz];
#pragma unroll
      for (int nd = 0; nd < 4; ++nd) {
        bf16x8 vf = *(const bf16x8*)&sv[(ks * 64 + nd * 16 + l16) * 32 + swz];
        oacc[c][nd] = __builtin_amdgcn_mfma_f32_16x16x32_bf16(wa, vf, oacc[c][nd], 0, 0, 0);
      }
    }
  }

  // ---- store attention output (bf16, head-major D layout) ----
#pragma unroll
  for (int c = 0; c < 4; ++c)
#pragma unroll
    for (int nd = 0; nd < 4; ++nd)
#pragma unroll
      for (int rr = 0; rr < 4; ++rr) {
        const int srow = s0 + wv * 16 + quad * 4 + rr;
        og[((size_t)((c * 2 + b) * 4096 + srow)) * 1536 + h * 64 + nd * 16 + l16] =
            f2bf(oacc[c][nd][rr]);
      }
}

// ---------------------------------------------------------------------------
extern "C" void kernel_launch(void* const* d_in, const int* in_sizes, int n_in,
                              void* d_out, int out_size, void* d_ws, size_t ws_size,
                              hipStream_t stream) {
  (void)in_sizes; (void)n_in; (void)out_size; (void)ws_size;
  const float* hs  = (const float*)d_in[0];
  const float* ehs = (const float*)d_in[1];
  const float* Wq  = (const float*)d_in[2];
  const float* bq  = (const float*)d_in[3];
  const float* Wk  = (const float*)d_in[4];
  const float* bk  = (const float*)d_in[5];
  const float* Wv  = (const float*)d_in[6];
  const float* bv  = (const float*)d_in[7];
  const float* Wo  = (const float*)d_in[8];
  const float* bo  = (const float*)d_in[9];
  float* out = (float*)d_out;

  u16* ws   = (u16*)d_ws;
  u16* hsb  = ws;               // [8*4096, 1536] bf16
  u16* ehsb = hsb + NHS;        // [8*154, 1536]  bf16
  u16* wqb  = ehsb + NEHS;
  u16* wkb  = wqb + NW;
  u16* wvb  = wkb + NW;
  u16* wob  = wvb + NW;
  u16* qb   = wob + NW;         // q  [8*4096, 1536] bf16
  u16* kgb  = qb + NHS;         // k  [8*154, 1536]  bf16
  u16* vtb  = kgb + NEHS;       // v^T [8][1536][160] bf16
  u16* atb  = vtb + NVT;        // attn out [8*4096, 1536] bf16

  auto cvt = [&](const float* s, u16* d, size_t n) {
    int n4 = (int)(n / 4);
    int blocks = (n4 + 255) / 256;
    if (blocks > 8192) blocks = 8192;
    cvt_bf16<<<blocks, 256, 0, stream>>>(s, d, n4);
  };
  cvt(hs, hsb, NHS);
  cvt(ehs, ehsb, NEHS);
  cvt(Wq, wqb, NW);
  cvt(Wk, wkb, NW);
  cvt(Wv, wvb, NW);
  cvt(Wo, wob, NW);

  gemm_bt<1><<<dim3(12, 256), 256, 0, stream>>>(hsb, wqb, bq, qb, 32768, 1536);
  gemm_bt<1><<<dim3(12, 10),  256, 0, stream>>>(ehsb, wkb, bk, kgb, 1232, 1536);
  gemm_bt<2><<<dim3(12, 10),  256, 0, stream>>>(ehsb, wvb, bv, vtb, 1232, 1536);

  attn_kernel<<<dim3(64, 24, 2), 256, 0, stream>>>(qb, kgb, vtb, atb);

  gemm_bt<0><<<dim3(12, 256), 256, 0, stream>>>(atb, wob, bo, out, 32768, 1536);
}